// Round 10
// baseline (976.864 us; speedup 1.0000x reference)
//
#include <hip/hip_runtime.h>

// 3x3 stride-1 VALID conv, NCHW fp32 in/out, bf16 MFMA implicit GEMM.
// N=16, Cin=Cout=32, 512x512 -> 510x510.
// R10 = R8 with ONE change: PT 256 -> 512 (full input row per block).
//  - Per row-iter each of the 32 input planes is touched with ONE 2KB
//    contiguous run (vs 1056B), each of the 32 output planes with a full
//    2040B row. Run length is the only lever that has moved BW so far
//    (264B->1056B gave 2.9->3.8 TB/s effective).
//  - No x-halo at all (input width == 512 == tile): clamp logic gone.
//  - LDS 3 slots x 514px x 80B = 120.5 KB -> dynamic LDS (+one-time
//    hipFuncSetAttribute; host-side, not stream-ordered, capture-safe).
//  - px 512/513 of each slot left unstaged: B-reads at kx=1,2 from px>=512
//    produce garbage only in MFMA columns whose store is guarded off.
//  - Register audit at the 1024-thread cap (128): afrag 36 + acc 48 +
//    bf(per-kx) 16 + buf 16 + misc ~15 ~= 131 -> watch FETCH/WRITE for
//    the R3 scratch-spill signature.

namespace {
constexpr int NI    = 16;
constexpr int C_IN  = 32;
constexpr int HI    = 512;
constexpr int WI    = 512;
constexpr int C_OUT = 32;
constexpr int HO    = 510;
constexpr int WO    = 510;

constexpr int RT    = 6;          // output rows per block (510/6 = 85 exact)
constexpr int PT    = 512;        // output x-pixels per block = full row
constexpr int XCOLS = 514;        // 512 staged + 2 pad px (reads only)
constexpr int PSTR  = 40;         // shorts per pixel (80B stride, 16B aligned)
constexpr int SLOTS = 3;          // LDS row ring
constexpr int SLOTW = XCOLS * PSTR;       // 20560 shorts per row slot
constexpr int LDS_BYTES = SLOTS * SLOTW * 2;  // 123360 B
constexpr int HIWI  = HI * WI;
constexpr int NT    = 1024;
}

typedef __attribute__((ext_vector_type(4))) float  floatx4;
typedef __attribute__((ext_vector_type(8))) __bf16 bf16x8;
typedef __attribute__((ext_vector_type(8))) unsigned short ushortx8;

// ---- weight prep: w [co][ci][3][3] f32 -> ws bf16 A-fragments [tap][h][lane][j]
// lane = quad*16 + l16; element j: co = h*16 + l16, ci = quad*8 + j.
__global__ void conv_wprep(const float* __restrict__ w, __bf16* __restrict__ ws) {
  const int t = threadIdx.x;
  for (int i = t; i < 9 * 2 * 64 * 8; i += 256) {
    const int j    = i & 7;
    const int lane = (i >> 3) & 63;
    const int h    = (i >> 9) & 1;
    const int tap  = i >> 10;
    const int co   = h * 16 + (lane & 15);
    const int ci   = (lane >> 4) * 8 + j;
    ws[i] = (__bf16)w[(co * C_IN + ci) * 9 + tap];
  }
}

__global__ __launch_bounds__(NT, 4)
void conv3x3_mfma(const float* __restrict__ x, const __bf16* __restrict__ ws,
                  const float* __restrict__ bias, float* __restrict__ out) {
  extern __shared__ __bf16 lds[];   // SLOTS * SLOTW bf16

  const int t    = threadIdx.x;
  const int lane = t & 63;
  const int wv   = t >> 6;        // 0..15
  const int quad = lane >> 4;
  const int l16  = lane & 15;
  const int ch   = wv >> 3;       // co-half: channels [ch*16, ch*16+16)
  const int w8   = wv & 7;        // px window [w8*64, w8*64+64)

  const int y0 = blockIdx.x * RT;
  const int n  = blockIdx.y;

  const float* xn = x + (size_t)n * C_IN * HIWI;

  // ---- staging: thread t covers px = t&511, ci-16-band cq = t>>9.
  // Per (cq,k) instruction-group the block reads 512 consecutive floats
  // = 2KB contiguous per plane (full input row; page-maximal run).
  // Commit packs 16 bf16 -> two ds_write_b128 at 80B lane stride.
  const int ps   = t & 511;
  const int cq   = t >> 9;                      // 0..1
  const int gofs = (cq * 16) * HIWI + ps;       // + k*HIWI + (y0+gr)*WI
  const int lofs = ps * PSTR + cq * 16;         // + slot*SLOTW (byte-16-aligned)

  auto issue = [&](int gr, float (&b)[16]) {    // 16 loads, stay in flight
    const float* rb = xn + (size_t)(y0 + gr) * WI;
#pragma unroll
    for (int k = 0; k < 16; ++k) b[k] = rb[gofs + k * HIWI];
  };
  auto commit = [&](int slot, float (&b)[16]) { // cvt + two b128 writes
    __bf16* s = lds + slot * SLOTW + lofs;
    union { __bf16 bb[16]; ushortx8 u[2]; } pk;
#pragma unroll
    for (int k = 0; k < 16; ++k) pk.bb[k] = (__bf16)b[k];
    *reinterpret_cast<ushortx8*>(s)     = pk.u[0];
    *reinterpret_cast<ushortx8*>(s + 8) = pk.u[1];
  };

  // ---- prologue: rows 0..2 staged (48 loads overlap)
  {
    float p0[16], p1[16], p2[16];
    issue(0, p0); issue(1, p1); issue(2, p2);
    commit(0, p0); commit(1, p1); commit(2, p2);
  }

  // ---- A fragments: 9 coalesced 16B loads from prepped ws (L2-resident).
  bf16x8 afrag[9];
#pragma unroll
  for (int tap = 0; tap < 9; ++tap)
    afrag[tap] = *reinterpret_cast<const bf16x8*>(ws + ((tap * 2 + ch) * 64 + lane) * 8);

  float bv[4];
#pragma unroll
  for (int r = 0; r < 4; ++r)
    bv[r] = bias[ch * 16 + quad * 4 + r];

  __syncthreads();

  const int pxb = w8 * 64 + l16;   // fragment f covers px = pxb + f*16
  floatx4 acc[3][4];               // rotating: output row o lives in acc[o%3]
  float buf[16];

#pragma unroll
  for (int ir = 0; ir < RT + 2; ++ir) {           // input rows y0+0 .. y0+7
    if (ir + 3 <= RT + 1) issue(ir + 3, buf);     // loads in flight across compute

    if (ir < RT) {                                // output row ir starts here
#pragma unroll
      for (int f = 0; f < 4; ++f)
        acc[ir % 3][f] = floatx4{bv[0], bv[1], bv[2], bv[3]};
    }

    // B-fragments read once per input row; bf held only per-kx (16 VGPR)
    const __bf16* sl = lds + (ir % SLOTS) * SLOTW + (w8 * 64 + l16) * PSTR + quad * 8;
#pragma unroll
    for (int kx = 0; kx < 3; ++kx) {
      bf16x8 bfr[4];
#pragma unroll
      for (int f = 0; f < 4; ++f)
        bfr[f] = *reinterpret_cast<const bf16x8*>(sl + (f * 16 + kx) * PSTR);
#pragma unroll
      for (int ky = 0; ky < 3; ++ky) {
        const int o = ir - ky;
        if (o < 0 || o >= RT) continue;
#pragma unroll
        for (int f = 0; f < 4; ++f)
          acc[o % 3][f] = __builtin_amdgcn_mfma_f32_16x16x32_bf16(
              afrag[ky * 3 + kx], bfr[f], acc[o % 3][f], 0, 0, 0);
      }
    }

    if (ir >= 2) {   // output row o = ir-2 complete; full-row runs per co-plane
      const int o = ir - 2;
      float* op = out + ((size_t)(n * C_OUT + ch * 16 + quad * 4) * HO + (y0 + o)) * WO + pxb;
#pragma unroll
      for (int f = 0; f < 4; ++f) {
        if (pxb + f * 16 < WO) {     // exact per-lane px guard (one px per lane/frag)
#pragma unroll
          for (int r = 0; r < 4; ++r)
            op[r * (HO * WO) + f * 16] = acc[o % 3][f][r];   // co = ch*16+quad*4+r
        }
      }
    }

    __syncthreads();                 // all waves done reading slot ir%3
    if (ir + 3 <= RT + 1)            // row ir+3 -> slot (ir+3)%3 == ir%3;
      commit(ir % SLOTS, buf);       // published by the next two barriers
  }
}

extern "C" void kernel_launch(void* const* d_in, const int* in_sizes, int n_in,
                              void* d_out, int out_size, void* d_ws, size_t ws_size,
                              hipStream_t stream) {
  const float* x    = (const float*)d_in[0];
  const float* w    = (const float*)d_in[1];
  const float* bias = (const float*)d_in[2];
  float* out        = (float*)d_out;
  __bf16* ws        = (__bf16*)d_ws;          // needs 18432 B

  static bool lds_cfg = false;                // one-time, host-side, capture-safe
  if (!lds_cfg) {
    hipFuncSetAttribute((const void*)conv3x3_mfma,
                        hipFuncAttributeMaxDynamicSharedMemorySize, LDS_BYTES);
    lds_cfg = true;
  }

  conv_wprep<<<dim3(1), 256, 0, stream>>>(w, ws);

  dim3 grid(HO / RT, NI);  // 85 x 16 = 1360 blocks, 1024 threads
  conv3x3_mfma<<<grid, NT, LDS_BYTES, stream>>>(x, ws, bias, out);
}

// Round 11
// 952.976 us; speedup vs baseline: 1.0251x; 1.0251x over previous
//
#include <hip/hip_runtime.h>

// 3x3 stride-1 VALID conv, NCHW fp32 in/out, bf16 MFMA implicit GEMM.
// N=16, Cin=Cout=32, 512x512 -> 510x510.
// R11 = R10's PT=512 (full-row tile: 16KB sequential reads per plane per
// block) rerun WITHOUT the register-pressure contamination that broke R10:
//  - NO row-reuse: classic ky-loop (reads 3 row slots per output row).
//    acc[4]=16 regs instead of acc[3][4]=48. LDS re-reads triple but LDS
//    is at ~36% utilization, far off the critical path.
//  - Register audit: afrag 36 + acc 16 + bfr 16 + buf 16 + addr ~15 ~= 99
//    <= 128 cap; amdgpu_waves_per_eu(4,4) pins the allocator at the full
//    128 budget (R10's compiler under-chose 64 and spilled: WRITE +88MB).
//  - R7-style ring: issue(o+3) at top, 2 barriers per row (slot o%3 is
//    read by iters o-2..o, so commit needs read-done + publish barriers).
//  - XCD y-swizzle (1360 blocks = 8*170, bijective): y-consecutive blocks
//    share an XCD L2 -> halo rows hit local L2.
// Tripwires: VGPR_Count must be ~100 (64 => allocator failed again);
// WRITE_SIZE must be ~585MB (more => spill).

namespace {
constexpr int NI    = 16;
constexpr int C_IN  = 32;
constexpr int HI    = 512;
constexpr int WI    = 512;
constexpr int C_OUT = 32;
constexpr int HO    = 510;
constexpr int WO    = 510;

constexpr int RT    = 6;          // output rows per block (510/6 = 85 exact)
constexpr int XCOLS = 514;        // 512 staged + 2 pad px (reads only)
constexpr int PSTR  = 40;         // shorts per pixel (80B stride, 16B aligned)
constexpr int SLOTS = 3;          // LDS row ring
constexpr int SLOTW = XCOLS * PSTR;           // 20560 shorts per row slot
constexpr int LDS_BYTES = SLOTS * SLOTW * 2;  // 123360 B
constexpr int HIWI  = HI * WI;
constexpr int NT    = 1024;
}

typedef __attribute__((ext_vector_type(4))) float  floatx4;
typedef __attribute__((ext_vector_type(8))) __bf16 bf16x8;
typedef __attribute__((ext_vector_type(8))) unsigned short ushortx8;

// ---- weight prep: w [co][ci][3][3] f32 -> ws bf16 A-fragments [tap][h][lane][j]
// lane = quad*16 + l16; element j: co = h*16 + l16, ci = quad*8 + j.
__global__ void conv_wprep(const float* __restrict__ w, __bf16* __restrict__ ws) {
  const int t = threadIdx.x;
  for (int i = t; i < 9 * 2 * 64 * 8; i += 256) {
    const int j    = i & 7;
    const int lane = (i >> 3) & 63;
    const int h    = (i >> 9) & 1;
    const int tap  = i >> 10;
    const int co   = h * 16 + (lane & 15);
    const int ci   = (lane >> 4) * 8 + j;
    ws[i] = (__bf16)w[(co * C_IN + ci) * 9 + tap];
  }
}

__global__ __launch_bounds__(NT)
__attribute__((amdgpu_waves_per_eu(4, 4)))
void conv3x3_mfma(const float* __restrict__ x, const __bf16* __restrict__ ws,
                  const float* __restrict__ bias, float* __restrict__ out) {
  extern __shared__ __bf16 lds[];   // SLOTS * SLOTW bf16

  const int t    = threadIdx.x;
  const int lane = t & 63;
  const int wv   = t >> 6;        // 0..15
  const int quad = lane >> 4;
  const int l16  = lane & 15;
  const int ch   = wv >> 3;       // co-half: channels [ch*16, ch*16+16)
  const int w8   = wv & 7;        // px window [w8*64, w8*64+64)

  // ---- XCD-aware remap: block L runs work wid = (L&7)*170 + (L>>3);
  // each XCD gets 170 consecutive wids = full y-runs (y fastest in wid).
  const int L   = blockIdx.x + 85 * blockIdx.y;   // grid 85 x 16 = 1360 = 8*170
  const int wid = (L & 7) * 170 + (L >> 3);
  const int y0  = (wid % 85) * RT;
  const int n   = wid / 85;

  const float* xn = x + (size_t)n * C_IN * HIWI;

  // ---- staging: thread t covers px = t&511, ci-16-band cq = t>>9.
  // Per (cq,k) instruction-group the block reads 512 consecutive floats =
  // 2KB contiguous per plane; consecutive row-iters extend this to a fully
  // sequential 16KB/plane/block stream (the run-length lever, 16x R8).
  // Commit packs 16 bf16 -> two ds_write_b128 at 80B lane stride.
  const int ps   = t & 511;
  const int cq   = t >> 9;                      // 0..1
  const int gofs = (cq * 16) * HIWI + ps;       // + k*HIWI + (y0+gr)*WI
  const int lofs = ps * PSTR + cq * 16;         // + slot*SLOTW (16B aligned)

  auto issue = [&](int gr, float (&b)[16]) {    // 16 loads, stay in flight
    const float* rb = xn + (size_t)(y0 + gr) * WI;
#pragma unroll
    for (int k = 0; k < 16; ++k) b[k] = rb[gofs + k * HIWI];
  };
  auto commit = [&](int slot, float (&b)[16]) { // cvt + two b128 writes
    __bf16* s = lds + slot * SLOTW + lofs;
    union { __bf16 bb[16]; ushortx8 u[2]; } pk;
#pragma unroll
    for (int k = 0; k < 16; ++k) pk.bb[k] = (__bf16)b[k];
    *reinterpret_cast<ushortx8*>(s)     = pk.u[0];
    *reinterpret_cast<ushortx8*>(s + 8) = pk.u[1];
  };

  // ---- prologue: rows 0..2 staged (48 loads overlap)
  {
    float p0[16], p1[16], p2[16];
    issue(0, p0); issue(1, p1); issue(2, p2);
    commit(0, p0); commit(1, p1); commit(2, p2);
  }

  // ---- A fragments: 9 coalesced 16B loads from prepped ws (L2-resident).
  bf16x8 afrag[9];
#pragma unroll
  for (int tap = 0; tap < 9; ++tap)
    afrag[tap] = *reinterpret_cast<const bf16x8*>(ws + ((tap * 2 + ch) * 64 + lane) * 8);

  float bv[4];
#pragma unroll
  for (int r = 0; r < 4; ++r)
    bv[r] = bias[ch * 16 + quad * 4 + r];

  __syncthreads();

  const int pxb = w8 * 64 + l16;   // fragment f covers px = pxb + f*16
  float buf[16];

#pragma unroll
  for (int o = 0; o < RT; ++o) {               // output rows y0+0 .. y0+5
    if (o + 3 <= RT + 1) issue(o + 3, buf);    // loads in flight across compute

    floatx4 acc[4];
#pragma unroll
    for (int f = 0; f < 4; ++f)
      acc[f] = floatx4{bv[0], bv[1], bv[2], bv[3]};

#pragma unroll
    for (int ky = 0; ky < 3; ++ky) {
      const __bf16* sl = lds + ((o + ky) % SLOTS) * SLOTW
                       + (w8 * 64 + l16) * PSTR + quad * 8;
#pragma unroll
      for (int kx = 0; kx < 3; ++kx) {
        bf16x8 bfr[4];
#pragma unroll
        for (int f = 0; f < 4; ++f)
          bfr[f] = *reinterpret_cast<const bf16x8*>(sl + (f * 16 + kx) * PSTR);
#pragma unroll
        for (int f = 0; f < 4; ++f)
          acc[f] = __builtin_amdgcn_mfma_f32_16x16x32_bf16(
              afrag[ky * 3 + kx], bfr[f], acc[f], 0, 0, 0);
      }
    }

    // store: full-row (2040B) runs per co-plane per block-row
    float* op = out + ((size_t)(n * C_OUT + ch * 16 + quad * 4) * HO + (y0 + o)) * WO + pxb;
#pragma unroll
    for (int f = 0; f < 4; ++f) {
      if (pxb + f * 16 < WO) {     // per-lane px guard (one px per lane/frag)
#pragma unroll
        for (int r = 0; r < 4; ++r)
          op[r * (HO * WO) + f * 16] = acc[f][r];   // co = ch*16+quad*4+r
      }
    }

    __syncthreads();               // all waves done reading slots o..o+2
    if (o + 3 <= RT + 1)
      commit(o % SLOTS, buf);      // row o+3 -> slot (o+3)%3 == o%3
    __syncthreads();               // publish before iter o+1 reads it
  }
}

extern "C" void kernel_launch(void* const* d_in, const int* in_sizes, int n_in,
                              void* d_out, int out_size, void* d_ws, size_t ws_size,
                              hipStream_t stream) {
  const float* x    = (const float*)d_in[0];
  const float* w    = (const float*)d_in[1];
  const float* bias = (const float*)d_in[2];
  float* out        = (float*)d_out;
  __bf16* ws        = (__bf16*)d_ws;          // needs 18432 B

  static bool lds_cfg = false;                // one-time, host-side, capture-safe
  if (!lds_cfg) {
    hipFuncSetAttribute((const void*)conv3x3_mfma,
                        hipFuncAttributeMaxDynamicSharedMemorySize, LDS_BYTES);
    lds_cfg = true;
  }

  conv_wprep<<<dim3(1), 256, 0, stream>>>(w, ws);

  dim3 grid(HO / RT, NI);  // 85 x 16 = 1360 blocks, 1024 threads
  conv3x3_mfma<<<grid, NT, LDS_BYTES, stream>>>(x, ws, bias, out);
}

// Round 12
// 898.752 us; speedup vs baseline: 1.0869x; 1.0603x over previous
//
#include <hip/hip_runtime.h>

// 3x3 stride-1 VALID conv, NCHW fp32 in/out, bf16 MFMA implicit GEMM.
// N=16, Cin=Cout=32, 512x512 -> 510x510.
// R12 = R8 (best: PT=256/RT=6, row-reuse, b128 LDS, 1 barrier/row) plus
// ONE change: STORE BOUNCE through LDS.
//   Before: stores were scalar dwords, one wave-instr scattering 4B x 64
//   lanes over 4 co-planes = 64B runs per plane per instruction (the
//   shortest-granularity stream left; reads proved granularity is the
//   only lever that moves BW on this pattern).
//   After: acc -> LDS out-buffer [co][px] (stride 260 words, 16B-aligned,
//   2-way banks = free class); post-barrier each wave reads one co-plane
//   row (conflict-free b128) and stores ONE dwordx4 instr = 1KB
//   contiguous per plane.
//   2-slot out ring, race-safe with the single barrier: store-reads of
//   out[p] drain at the next barrier's lgkmcnt(0); out[p] is rewritten
//   two iterations later.
// LDS: 63360 (stage ring) + 2*33280 (out ring) = 129920 B dynamic.
// Registers: R8's ~113 + ~4 addressing <= 128 cap (16 waves). Tripwire:
// WRITE_SIZE inflation = scratch spill (R3/R10 lesson).

namespace {
constexpr int NI    = 16;
constexpr int C_IN  = 32;
constexpr int HI    = 512;
constexpr int WI    = 512;
constexpr int C_OUT = 32;
constexpr int HO    = 510;
constexpr int WO    = 510;

constexpr int RT    = 6;          // output rows per block (510/6 = 85 exact)
constexpr int PT    = 256;        // output x-pixels per block
constexpr int XCOLS = 264;        // staged px per row: 256 core + 8 halo
constexpr int PSTR  = 40;         // shorts per pixel (80B stride, 16B aligned)
constexpr int SLOTS = 3;          // staging row ring
constexpr int SLOTW = XCOLS * PSTR;       // 10560 shorts per stage slot
constexpr int OSTR  = 260;        // out-buffer px stride in f32 words (1040B: 16B-aligned, 2-way banks)
constexpr int OSLOT = OSTR * 32;  // 8320 words per out slot
constexpr int LDS_BYTES = SLOTS * SLOTW * 2 + 2 * OSLOT * 4;  // 129920 B
constexpr int HIWI  = HI * WI;
constexpr int HOWO  = HO * WO;
constexpr int NT    = 1024;
}

typedef __attribute__((ext_vector_type(4))) float  floatx4;
typedef __attribute__((ext_vector_type(8))) __bf16 bf16x8;
typedef __attribute__((ext_vector_type(8))) unsigned short ushortx8;

// ---- weight prep: w [co][ci][3][3] f32 -> ws bf16 A-fragments [tap][h][lane][j]
// lane = quad*16 + l16; element j: co = h*16 + l16, ci = quad*8 + j.
__global__ void conv_wprep(const float* __restrict__ w, __bf16* __restrict__ ws) {
  const int t = threadIdx.x;
  for (int i = t; i < 9 * 2 * 64 * 8; i += 256) {
    const int j    = i & 7;
    const int lane = (i >> 3) & 63;
    const int h    = (i >> 9) & 1;
    const int tap  = i >> 10;
    const int co   = h * 16 + (lane & 15);
    const int ci   = (lane >> 4) * 8 + j;
    ws[i] = (__bf16)w[(co * C_IN + ci) * 9 + tap];
  }
}

__global__ __launch_bounds__(NT)
__attribute__((amdgpu_waves_per_eu(4, 4)))
void conv3x3_mfma(const float* __restrict__ x, const __bf16* __restrict__ ws,
                  const float* __restrict__ bias, float* __restrict__ out) {
  extern __shared__ __bf16 lds[];                       // stage ring
  float* outbuf = (float*)(lds + SLOTS * SLOTW);        // out ring (16B-aligned: 63360%16==0)

  const int t    = threadIdx.x;
  const int lane = t & 63;
  const int wv   = t >> 6;        // 0..15
  const int quad = lane >> 4;
  const int l16  = lane & 15;
  const int ch   = wv >> 3;       // co-half: channels [ch*16, ch*16+16)
  const int w8   = wv & 7;        // px window [w8*32, w8*32+32)

  const int x0 = blockIdx.x * PT;
  const int y0 = blockIdx.y * RT;
  const int n  = blockIdx.z;

  const float* xn = x + (size_t)n * C_IN * HIWI;

  // ---- staging geometry (R8): thread t covers core px = t&255, ci octet
  // cq = t>>8. Per (cq,k) instruction-group: 256 consecutive px = 1KB
  // contiguous per plane. Commit packs 8 bf16 -> one ds_write_b128.
  const int ps   = t & 255;
  const int cq   = t >> 8;                      // 0..3
  const int gofs = (cq * 8) * HIWI + x0 + ps;   // + k*HIWI + (y0+gr)*WI
  const int lofs = ps * PSTR + cq * 8;          // + slot*SLOTW

  // halo px 256..263 (x0=0: real; x0=256: clamped, feeds only invalid outputs)
  const bool hw  = (wv < 4);
  const int hci  = t >> 3;                      // 0..31 for t<256
  const int hpx  = 256 + (t & 7);
  int hgx = x0 + hpx; if (hgx > WI - 1) hgx = WI - 1;
  const int hgo  = hci * HIWI + hgx;
  const int hlo  = hpx * PSTR + hci;

  auto issue = [&](int gr, float (&b)[8], float& h) {   // 8(+1) loads, in flight
    const float* rb = xn + (size_t)(y0 + gr) * WI;
#pragma unroll
    for (int k = 0; k < 8; ++k) b[k] = rb[gofs + k * HIWI];
    if (hw) h = rb[hgo];
  };
  auto commit = [&](int slot, float (&b)[8], float h) { // cvt + one b128 write
    __bf16* s = lds + slot * SLOTW;
    union { __bf16 bb[8]; ushortx8 u; } pk;
#pragma unroll
    for (int k = 0; k < 8; ++k) pk.bb[k] = (__bf16)b[k];
    *reinterpret_cast<ushortx8*>(s + lofs) = pk.u;      // 16B aligned
    if (hw) s[hlo] = (__bf16)h;
  };

  // ---- prologue: rows 0..2 staged with overlapped loads
  {
    float p0[8], p1[8], p2[8];
    float h0 = 0.f, h1 = 0.f, h2 = 0.f;
    issue(0, p0, h0); issue(1, p1, h1); issue(2, p2, h2);
    commit(0, p0, h0); commit(1, p1, h1); commit(2, p2, h2);
  }

  // ---- A fragments: 9 coalesced 16B loads from prepped ws (L2-resident).
  bf16x8 afrag[9];
#pragma unroll
  for (int tap = 0; tap < 9; ++tap)
    afrag[tap] = *reinterpret_cast<const bf16x8*>(ws + ((tap * 2 + ch) * 64 + lane) * 8);

  float bv[4];
#pragma unroll
  for (int r = 0; r < 4; ++r)
    bv[r] = bias[ch * 16 + quad * 4 + r];

  __syncthreads();

  floatx4 acc[3][2];                    // rotating: output row o lives in acc[o%3]
  float buf[8]; float hb = 0.f;

#pragma unroll
  for (int ir = 0; ir < RT + 2; ++ir) {           // input rows y0+0 .. y0+7
    if (ir + 3 <= RT + 1) issue(ir + 3, buf, hb); // loads in flight across compute

    if (ir < RT) {                                // output row ir starts here
#pragma unroll
      for (int f = 0; f < 2; ++f)
        acc[ir % 3][f] = floatx4{bv[0], bv[1], bv[2], bv[3]};
    }

    // read this input row's 6 B-fragments ONCE (single b128 each)
    bf16x8 bfr[2][3];
    const __bf16* sl = lds + (ir % SLOTS) * SLOTW + (w8 * 32 + l16) * PSTR + quad * 8;
#pragma unroll
    for (int f = 0; f < 2; ++f)
#pragma unroll
      for (int kx = 0; kx < 3; ++kx)
        bfr[f][kx] = *reinterpret_cast<const bf16x8*>(sl + (f * 16 + kx) * PSTR);

    // each fragment feeds up to 3 output rows (ky = ir - o)
#pragma unroll
    for (int ky = 0; ky < 3; ++ky) {
      const int o = ir - ky;
      if (o < 0 || o >= RT) continue;
#pragma unroll
      for (int kx = 0; kx < 3; ++kx)
#pragma unroll
        for (int f = 0; f < 2; ++f)
          acc[o % 3][f] = __builtin_amdgcn_mfma_f32_16x16x32_bf16(
              afrag[ky * 3 + kx], bfr[f][kx], acc[o % 3][f], 0, 0, 0);
    }

    const int o = ir - 2;              // output row completed this iter
    if (o >= 0) {
      // acc -> out-buffer [co][px] (scalar writes, 2-way banks = free class)
      float* ob = outbuf + (o & 1) * OSLOT;
#pragma unroll
      for (int f = 0; f < 2; ++f)
#pragma unroll
        for (int r = 0; r < 4; ++r)
          ob[(ch * 16 + quad * 4 + r) * OSTR + w8 * 32 + f * 16 + l16] = acc[o % 3][f][r];
    }

    __syncthreads();                   // stage reads done + out-writes published
    if (ir + 3 <= RT + 1)
      commit(ir % SLOTS, buf, hb);     // row ir+3 -> slot (ir+3)%3 == ir%3

    if (o >= 0) {
      // coalesced store: wave wv stores plane p*16+wv, one dwordx4 instr
      // = 64 lanes x 16B = 1KB contiguous per plane per instruction.
      const float* ob = outbuf + (o & 1) * OSLOT;
#pragma unroll
      for (int p = 0; p < 2; ++p) {
        const int co = p * 16 + wv;
        const floatx4 v = *reinterpret_cast<const floatx4*>(ob + co * OSTR + 4 * lane);
        const int gx = x0 + 4 * lane;
        float* dst = out + ((size_t)(n * C_OUT + co) * HO + (y0 + o)) * WO + gx;
        if (gx + 3 < WO) {
          *reinterpret_cast<floatx4*>(dst) = v;
        } else {                       // only x0=256, lane 63: px 508..511 -> 2 valid
          if (gx < WO)     dst[0] = v.x;
          if (gx + 1 < WO) dst[1] = v.y;
          if (gx + 2 < WO) dst[2] = v.z;
        }
      }
    }
  }
}

extern "C" void kernel_launch(void* const* d_in, const int* in_sizes, int n_in,
                              void* d_out, int out_size, void* d_ws, size_t ws_size,
                              hipStream_t stream) {
  const float* x    = (const float*)d_in[0];
  const float* w    = (const float*)d_in[1];
  const float* bias = (const float*)d_in[2];
  float* out        = (float*)d_out;
  __bf16* ws        = (__bf16*)d_ws;          // needs 18432 B

  static bool lds_cfg = false;                // one-time, host-side, capture-safe
  if (!lds_cfg) {
    hipFuncSetAttribute((const void*)conv3x3_mfma,
                        hipFuncAttributeMaxDynamicSharedMemorySize, LDS_BYTES);
    lds_cfg = true;
  }

  conv_wprep<<<dim3(1), 256, 0, stream>>>(w, ws);

  dim3 grid(WI / PT, HO / RT, NI);  // 2 x 85 x 16 = 2720 blocks, 1024 threads
  conv3x3_mfma<<<grid, NT, LDS_BYTES, stream>>>(x, ws, bias, out);
}